// Round 3
// baseline (212.528 us; speedup 1.0000x reference)
//
#include <hip/hip_runtime.h>
#include <math.h>

#define NT 256
#define MAXG 1536   // actual G ~= 1366; LDS: 1536*8*4 + 1536*8 = 61.4 KB

struct PassOut { double err; int idx; };

__global__ __launch_bounds__(NT, 2)
void e8p_quant_kernel(const float* __restrict__ X,
                      const float* __restrict__ grid_part,
                      const float* __restrict__ grid_norm,
                      const int* __restrict__ pam,
                      float* __restrict__ out,
                      int N, int G)
{
#pragma clang fp contract(off)
    __shared__ float  lg[MAXG * 8];
    __shared__ double lnrm[MAXG];

    // Stage grid into LDS (g[8] f32 per point + f64 norm).
    const float4* gp4 = reinterpret_cast<const float4*>(grid_part);
    float4* lg4w = reinterpret_cast<float4*>(lg);
    for (int j = threadIdx.x; j < G; j += NT) {
        lg4w[2 * j]     = gp4[2 * j];
        lg4w[2 * j + 1] = gp4[2 * j + 1];
        lnrm[j] = (double)grid_norm[j];   // norms are multiples of 0.25: exact
    }
    __syncthreads();

    int r = blockIdx.x * NT + threadIdx.x;
    if (r >= N) return;

    const float4* x4 = reinterpret_cast<const float4*>(X);
    float4 a0 = x4[2 * r], a1 = x4[2 * r + 1];
    float xf[8] = {a0.x, a0.y, a0.z, a0.w, a1.x, a1.y, a1.z, a1.w};

    // f64 shifted parts: xd +- 0.25 is EXACT in f64 (no rounding, unlike f32).
    double xp[8], xm[8];
    int nbp = 0, nbm = 0;
#pragma unroll
    for (int k = 0; k < 8; ++k) {
        double xd = (double)xf[k];
        double sp = xd + 0.25, sm = xd - 0.25;
        nbp |= int(sp < 0.0) << k;
        nbm |= int(sm < 0.0) << k;
        xp[k] = fabs(sp); xm[k] = fabs(sm);
    }
    int oddp = __popc(nbp) & 1, oddm = __popc(nbm) & 1;
    if (oddp) xp[7] = -xp[7];
    if (oddm) xm[7] = -xm[7];
    int msbp = nbp ^ (oddp << 7);   // mask sign bits (1 = negative)
    int msbm = nbm ^ (oddm << 7);

    // Brute-force argmax. In f64 the whole score is EXACT real arithmetic:
    // products (24-bit mantissa x) * (half-integer g) need <=27 bits; the
    // summed/scaled score <=34 bits. So argmax == true argmax, ties first-wins.
    const float4* lg4 = reinterpret_cast<const float4*>(lg);
    double bp = -1.0e300, bm = -1.0e300;
    int ip = 0, im = 0;
    for (int j = 0; j < G; ++j) {
        float4 ga = lg4[2 * j], gb = lg4[2 * j + 1];
        double nrm = lnrm[j];
        double g0 = (double)ga.x, g1 = (double)ga.y, g2 = (double)ga.z, g3 = (double)ga.w;
        double g4 = (double)gb.x, g5 = (double)gb.y, g6 = (double)gb.z, g7 = (double)gb.w;
        double dp = xp[0] * g0;
        dp = fma(xp[1], g1, dp); dp = fma(xp[2], g2, dp); dp = fma(xp[3], g3, dp);
        dp = fma(xp[4], g4, dp); dp = fma(xp[5], g5, dp); dp = fma(xp[6], g6, dp);
        dp = fma(xp[7], g7, dp);
        double dm = xm[0] * g0;
        dm = fma(xm[1], g1, dm); dm = fma(xm[2], g2, dm); dm = fma(xm[3], g3, dm);
        dm = fma(xm[4], g4, dm); dm = fma(xm[5], g5, dm); dm = fma(xm[6], g6, dm);
        dm = fma(xm[7], g7, dm);
        double sp = fma(2.0, dp, -nrm);   // exact
        double sm = fma(2.0, dm, -nrm);   // exact
        if (sp > bp) { bp = sp; ip = j; }
        if (sm > bm) { bm = sm; im = j; }
    }

    auto finish = [&](int bi, double sgn_quarter, int msb, int par, double* v) -> PassOut {
#pragma clang fp contract(off)
        float4 ga = lg4[2 * bi], gb = lg4[2 * bi + 1];
        float g[8] = {ga.x, ga.y, ga.z, ga.w, gb.x, gb.y, gb.z, gb.w};
        int gneg = 0; float sumabs = 0.0f;
#pragma unroll
        for (int k = 0; k < 8; ++k) {
            gneg |= int(g[k] < 0.0f) << k;
            sumabs += fabsf(g[k]);   // exact integer in f32
        }
        double vv[8];
#pragma unroll
        for (int k = 0; k < 8; ++k) {  // vals = roundout * (+-1): exact sign flip
            unsigned u = __float_as_uint(g[k]) ^ ((((unsigned)msb >> k) & 1u) << 31);
            double val = (double)__uint_as_float(u);
            vv[k] = val;
            v[k] = val;
        }
        // err in f64: d exact; squares rounded once each (identical both sides);
        // numpy pairwise order for n=8; IEEE f64 sqrt.
        double d[8];
#pragma unroll
        for (int k = 0; k < 8; ++k) {
            double xs = (double)xf[k] + sgn_quarter;   // exact
            d[k] = xs - vv[k];                         // exact
        }
        double s0 = d[0]*d[0], s1 = d[1]*d[1], s2 = d[2]*d[2], s3 = d[3]*d[3];
        double s4 = d[4]*d[4], s5 = d[5]*d[5], s6 = d[6]*d[6], s7 = d[7]*d[7];
        double e = ((s0 + s1) + (s2 + s3)) + ((s4 + s5) + (s6 + s7));
        double err = sqrt(e);
        int godd = ((int)(sumabs + 0.5f)) & 1;   // == grid_abs_odd[abs_idx]
        int sb = gneg ^ msb;                     // (roundout<0) ^ (mask<0)
        // permute [0,2,4,6,1,3,5,7]; bit0 ^= parity; bit7 ^= grid_abs_odd
        int mi = (((sb >> 0) & 1) ^ par)
               | (((sb >> 2) & 1) << 1)
               | (((sb >> 4) & 1) << 2)
               | (((sb >> 6) & 1) << 3)
               | (((sb >> 1) & 1) << 4)
               | (((sb >> 3) & 1) << 5)
               | (((sb >> 5) & 1) << 6)
               | ((((sb >> 7) & 1) ^ godd) << 7);
        PassOut po;
        po.err = err;
        po.idx = (pam[bi] << 8) + mi;
        return po;
    };

    double vp[8], vm[8];
    PassOut P = finish(ip, +0.25, msbp, 1, vp);
    PassOut M = finish(im, -0.25, msbm, 0, vm);
    bool which = P.err < M.err;   // strict <, matches ref

    float ov[8];
#pragma unroll
    for (int k = 0; k < 8; ++k) {
        double o = which ? (vp[k] - 0.25) : (vm[k] + 0.25);  // exact in f64
        ov[k] = (float)o;
    }

    float4* o4 = reinterpret_cast<float4*>(out + (size_t)r * 8);
    o4[0] = make_float4(ov[0], ov[1], ov[2], ov[3]);
    o4[1] = make_float4(ov[4], ov[5], ov[6], ov[7]);
    out[(size_t)N * 8 + r] = (float)(which ? P.idx : M.idx);  // idx < 2^16: exact
}

extern "C" void kernel_launch(void* const* d_in, const int* in_sizes, int n_in,
                              void* d_out, int out_size, void* d_ws, size_t ws_size,
                              hipStream_t stream)
{
    const float* X   = (const float*)d_in[0];
    const float* gp  = (const float*)d_in[1];
    const float* gn  = (const float*)d_in[2];
    const int*   pam = (const int*)d_in[3];
    float* out = (float*)d_out;

    int N = in_sizes[0] / 8;
    int G = in_sizes[1] / 8;
    int blocks = (N + NT - 1) / NT;
    e8p_quant_kernel<<<blocks, NT, 0, stream>>>(X, gp, gn, pam, out, N, G);
}